// Round 1
// 278.298 us; speedup vs baseline: 1.0306x; 1.0306x over previous
//
#include <hip/hip_runtime.h>

// x: [16,128,128,128] fp32 ; pixel_shuffle(2) -> [16,32,256,256]
// 4x4 separable FIR (outer([1,3,3,1])/64), pad=2 -> out [16,32,257,257]
//
// R2: 8 outputs per thread along w. The 11-tap shuffled-col window for
// outputs 8g..8g+7 needs even-parity dwords wi=4g-1..4g+4 (6) and odd-parity
// dwords wi=4g-1..4g+3 (5): one aligned float4 + 2 scalars (even plane) and
// one aligned float4 + 1 scalar (odd plane) per shuffled row. Boundary
// zero-pad folded into per-thread loop-invariant value masks. Vertical 4-tap
// via rolling window of 8-wide horizontal results.
//
// R3: TY 16 -> 8. Old grid was 66x17 = 1122 blocks = 4.4 blocks/CU, capping
// occupancy at ~55% (measured 33%) while VGPR=48 (<=64) permits 8 blocks/CU.
// Latency-bound per rocprof (VALUBusy 10%, HBM 29% achievable, Occ 33%).
// TY=8 -> 66x33 = 2178 blocks = 8.5 blocks/CU: one full residency round,
// ~8 waves/SIMD so TLP covers the ~600cy load latency of the serial
// load->FIR->store chain. Redundant strip-prologue rows: 11/8 vs 19/16
// (+16% issued loads, L2/L3-absorbed). Invariant: keep VGPR <= 64 — waves/CU
// halve past that, which is worth more than any ILP trick here.
constexpr int Bn = 16;
constexpr int Hn = 128;
constexpr int Wn = 128;
constexpr int Cc = 32;
constexpr int SH = 2 * Hn;   // 256
constexpr int SW = 2 * Wn;   // 256
constexpr int OH = SH + 1;   // 257
constexpr int OW = SW + 1;   // 257
constexpr int HW = Hn * Wn;  // plane stride
constexpr int NG = 33;       // ceil(257/8) column groups of 8 outputs
constexpr int TY = 8;        // output rows per thread
constexpr int NSTRIP = (OH + TY - 1) / TY;        // 33
constexpr int NTHREADS = Bn * Cc * NG;            // 16896 = 66 * 256

__global__ __launch_bounds__(256) void upsamp_fir8(
    const float* __restrict__ x,
    const float* __restrict__ k4,
    float* __restrict__ out)
{
    const int tid = blockIdx.x * 256 + threadIdx.x;   // < 16896 exactly
    const int g  = tid % NG;
    const int bc = tid / NG;
    const float* xp = x + (size_t)bc * 4 * HW;

    // Separable taps from the rank-1, sum-1 kernel (exact: powers-of-two
    // scaled small ints), flipped for true convolution.
    float fh[4], fv[4];
#pragma unroll
    for (int j = 0; j < 4; ++j) fh[j] = k4[j] + k4[4+j] + k4[8+j] + k4[12+j];
#pragma unroll
    for (int i = 0; i < 4; ++i) fv[i] = k4[4*i] + k4[4*i+1] + k4[4*i+2] + k4[4*i+3];
    const float h0 = fh[3], h1 = fh[2], h2 = fh[1], h3 = fh[0];
    const float g0 = fv[3], g1 = fv[2], g2 = fv[1], g3 = fv[0];

    // Loop-invariant clamped addresses + boundary value masks.
    const int ci  = 4 * g;
    const int aM1 = ci - 1 < 0 ? 0 : ci - 1;          // wi = 4g-1 (E[0], O[0])
    const int a4  = ci > Wn - 4 ? Wn - 4 : ci;        // aligned float4 base
    const int aP4 = ci + 4 > Wn - 1 ? Wn - 1 : ci + 4;// wi = 4g+4 (E[5])
    float mE[6], mO[5];
#pragma unroll
    for (int i = 0; i < 6; ++i) { int w = 8*g - 2 + 2*i; mE[i] = (unsigned)w < (unsigned)SW ? 1.f : 0.f; }
#pragma unroll
    for (int i = 0; i < 5; ++i) { int w = 8*g - 1 + 2*i; mO[i] = (unsigned)w < (unsigned)SW ? 1.f : 0.f; }

    // Horizontal FIR for 8 outputs on shuffled row h.
    auto loadrow = [&](int h, float* V) {
        if ((unsigned)h >= (unsigned)SH) {
#pragma unroll
            for (int k = 0; k < 8; ++k) V[k] = 0.f;
            return;
        }
        const float* be = xp + (size_t)(2 * (h & 1)) * HW + (size_t)(h >> 1) * Wn;
        const float* bo = be + HW;
        float E[6], O[5];
        E[0] = be[aM1];
        float4 e4 = *(const float4*)(be + a4);   // 16B aligned: be,a4 mult of 4 dwords
        E[1] = e4.x; E[2] = e4.y; E[3] = e4.z; E[4] = e4.w;
        E[5] = be[aP4];
        O[0] = bo[aM1];
        float4 o4 = *(const float4*)(bo + a4);
        O[1] = o4.x; O[2] = o4.y; O[3] = o4.z; O[4] = o4.w;
#pragma unroll
        for (int i = 0; i < 6; ++i) E[i] *= mE[i];
#pragma unroll
        for (int i = 0; i < 5; ++i) O[i] *= mO[i];
#pragma unroll
        for (int k = 0; k < 8; k += 2) {
            int i = k >> 1;
            V[k]   = h0*E[i] + h1*O[i]   + h2*E[i+1] + h3*O[i+1];
            V[k+1] = h0*O[i] + h1*E[i+1] + h2*O[i+1] + h3*E[i+2];
        }
    };

    const int oh0 = blockIdx.y * TY;
    float va[8], vb[8], vc[8], vd[8];
    loadrow(oh0 - 2, va);
    loadrow(oh0 - 1, vb);
    loadrow(oh0,     vc);

    float* op = out + ((size_t)bc * OH + oh0) * OW + 8 * g;
    const int tmax = (OH - oh0) < TY ? (OH - oh0) : TY;
#pragma unroll 4
    for (int t = 0; t < tmax; ++t) {
        loadrow(oh0 + t + 1, vd);
        float o[8];
#pragma unroll
        for (int k = 0; k < 8; ++k)
            o[k] = g0*va[k] + g1*vb[k] + g2*vc[k] + g3*vd[k];
        float* p = op + (size_t)t * OW;
        if (g < NG - 1) {
#pragma unroll
            for (int k = 0; k < 8; ++k) p[k] = o[k];   // OW=257: rows only 4B aligned
        } else {
            p[0] = o[0];                               // ow = 256 only
        }
#pragma unroll
        for (int k = 0; k < 8; ++k) { va[k] = vb[k]; vb[k] = vc[k]; vc[k] = vd[k]; }
    }
}

extern "C" void kernel_launch(void* const* d_in, const int* in_sizes, int n_in,
                              void* d_out, int out_size, void* d_ws, size_t ws_size,
                              hipStream_t stream)
{
    const float* x  = (const float*)d_in[0];
    const float* k4 = (const float*)d_in[1];
    float* out      = (float*)d_out;

    dim3 grid(NTHREADS / 256, NSTRIP, 1);
    upsamp_fir8<<<grid, dim3(256), 0, stream>>>(x, k4, out);
}

// Round 2
// 277.603 us; speedup vs baseline: 1.0331x; 1.0025x over previous
//
#include <hip/hip_runtime.h>

// x: [16,128,128,128] fp32 ; pixel_shuffle(2) -> [16,32,256,256]
// 4x4 separable FIR (outer([1,3,3,1])/64), pad=2 -> out [16,32,257,257]
//
// R2: 8 outputs per thread along w. The 11-tap shuffled-col window for
// outputs 8g..8g+7 needs even-parity dwords wi=4g-1..4g+4 (6) and odd-parity
// dwords wi=4g-1..4g+3 (5): one aligned float4 + 2 scalars (even plane) and
// one aligned float4 + 1 scalar (odd plane) per shuffled row. Boundary
// zero-pad folded into per-thread loop-invariant value masks. Vertical 4-tap
// via rolling window of 8-wide horizontal results.
//
// R3: TY 16 -> 8 for occupancy (33% -> 43%, 123 -> 112 us).
//
// R4: TY 8 -> 9. R3's grid was 66x33 = 2178 blocks vs the 2048-block
// residency cap (8 blocks/CU @ VGPR<=64, 256 CU): two scheduling rounds,
// the second running 130 blocks at 6% occupancy for half the wall time
// (measured Occ 43% ~= (100+6)/2). TY=9 -> 66x29 = 1914 blocks: ONE round,
// no tail. Per-block work +9% (12 vs 11 loadrows), total time ~0.55x.
// Invariants: VGPR <= 64 (residency cap halves past it); grid <= 2048 blocks
// (one residency round) — tail rounds cost ~2x, worth more than per-block
// work minimization.
constexpr int Bn = 16;
constexpr int Hn = 128;
constexpr int Wn = 128;
constexpr int Cc = 32;
constexpr int SH = 2 * Hn;   // 256
constexpr int SW = 2 * Wn;   // 256
constexpr int OH = SH + 1;   // 257
constexpr int OW = SW + 1;   // 257
constexpr int HW = Hn * Wn;  // plane stride
constexpr int NG = 33;       // ceil(257/8) column groups of 8 outputs
constexpr int TY = 9;        // output rows per thread
constexpr int NSTRIP = (OH + TY - 1) / TY;        // 29
constexpr int NTHREADS = Bn * Cc * NG;            // 16896 = 66 * 256

__global__ __launch_bounds__(256) void upsamp_fir8(
    const float* __restrict__ x,
    const float* __restrict__ k4,
    float* __restrict__ out)
{
    const int tid = blockIdx.x * 256 + threadIdx.x;   // < 16896 exactly
    const int g  = tid % NG;
    const int bc = tid / NG;
    const float* xp = x + (size_t)bc * 4 * HW;

    // Separable taps from the rank-1, sum-1 kernel (exact: powers-of-two
    // scaled small ints), flipped for true convolution.
    float fh[4], fv[4];
#pragma unroll
    for (int j = 0; j < 4; ++j) fh[j] = k4[j] + k4[4+j] + k4[8+j] + k4[12+j];
#pragma unroll
    for (int i = 0; i < 4; ++i) fv[i] = k4[4*i] + k4[4*i+1] + k4[4*i+2] + k4[4*i+3];
    const float h0 = fh[3], h1 = fh[2], h2 = fh[1], h3 = fh[0];
    const float g0 = fv[3], g1 = fv[2], g2 = fv[1], g3 = fv[0];

    // Loop-invariant clamped addresses + boundary value masks.
    const int ci  = 4 * g;
    const int aM1 = ci - 1 < 0 ? 0 : ci - 1;          // wi = 4g-1 (E[0], O[0])
    const int a4  = ci > Wn - 4 ? Wn - 4 : ci;        // aligned float4 base
    const int aP4 = ci + 4 > Wn - 1 ? Wn - 1 : ci + 4;// wi = 4g+4 (E[5])
    float mE[6], mO[5];
#pragma unroll
    for (int i = 0; i < 6; ++i) { int w = 8*g - 2 + 2*i; mE[i] = (unsigned)w < (unsigned)SW ? 1.f : 0.f; }
#pragma unroll
    for (int i = 0; i < 5; ++i) { int w = 8*g - 1 + 2*i; mO[i] = (unsigned)w < (unsigned)SW ? 1.f : 0.f; }

    // Horizontal FIR for 8 outputs on shuffled row h.
    auto loadrow = [&](int h, float* V) {
        if ((unsigned)h >= (unsigned)SH) {
#pragma unroll
            for (int k = 0; k < 8; ++k) V[k] = 0.f;
            return;
        }
        const float* be = xp + (size_t)(2 * (h & 1)) * HW + (size_t)(h >> 1) * Wn;
        const float* bo = be + HW;
        float E[6], O[5];
        E[0] = be[aM1];
        float4 e4 = *(const float4*)(be + a4);   // 16B aligned: be,a4 mult of 4 dwords
        E[1] = e4.x; E[2] = e4.y; E[3] = e4.z; E[4] = e4.w;
        E[5] = be[aP4];
        O[0] = bo[aM1];
        float4 o4 = *(const float4*)(bo + a4);
        O[1] = o4.x; O[2] = o4.y; O[3] = o4.z; O[4] = o4.w;
#pragma unroll
        for (int i = 0; i < 6; ++i) E[i] *= mE[i];
#pragma unroll
        for (int i = 0; i < 5; ++i) O[i] *= mO[i];
#pragma unroll
        for (int k = 0; k < 8; k += 2) {
            int i = k >> 1;
            V[k]   = h0*E[i] + h1*O[i]   + h2*E[i+1] + h3*O[i+1];
            V[k+1] = h0*O[i] + h1*E[i+1] + h2*O[i+1] + h3*E[i+2];
        }
    };

    const int oh0 = blockIdx.y * TY;
    float va[8], vb[8], vc[8], vd[8];
    loadrow(oh0 - 2, va);
    loadrow(oh0 - 1, vb);
    loadrow(oh0,     vc);

    float* op = out + ((size_t)bc * OH + oh0) * OW + 8 * g;
    const int tmax = (OH - oh0) < TY ? (OH - oh0) : TY;
#pragma unroll 3
    for (int t = 0; t < tmax; ++t) {
        loadrow(oh0 + t + 1, vd);
        float o[8];
#pragma unroll
        for (int k = 0; k < 8; ++k)
            o[k] = g0*va[k] + g1*vb[k] + g2*vc[k] + g3*vd[k];
        float* p = op + (size_t)t * OW;
        if (g < NG - 1) {
#pragma unroll
            for (int k = 0; k < 8; ++k) p[k] = o[k];   // OW=257: rows only 4B aligned
        } else {
            p[0] = o[0];                               // ow = 256 only
        }
#pragma unroll
        for (int k = 0; k < 8; ++k) { va[k] = vb[k]; vb[k] = vc[k]; vc[k] = vd[k]; }
    }
}

extern "C" void kernel_launch(void* const* d_in, const int* in_sizes, int n_in,
                              void* d_out, int out_size, void* d_ws, size_t ws_size,
                              hipStream_t stream)
{
    const float* x  = (const float*)d_in[0];
    const float* k4 = (const float*)d_in[1];
    float* out      = (float*)d_out;

    dim3 grid(NTHREADS / 256, NSTRIP, 1);
    upsamp_fir8<<<grid, dim3(256), 0, stream>>>(x, k4, out);
}

// Round 3
// 249.017 us; speedup vs baseline: 1.1517x; 1.1148x over previous
//
#include <hip/hip_runtime.h>

// x: [16,128,128,128] fp32 ; pixel_shuffle(2) -> [16,32,256,256]
// 4x4 separable FIR (outer([1,3,3,1])/64), pad=2 -> out [16,32,257,257]
//
// R5: full restructure to LDS-staged stencil, 1 thread = 1 output column.
// Why: R3/R4 falsified the occupancy theory (grid 2178->1914 blocks, dur
// flat 112us, Occ flat 43%). Real bottleneck: transaction economy + serial
// chains. Old kernel: 8 consecutive cols/thread -> each scalar store instr
// had 32B lane stride = 32 cache lines per 256B written (8x amplification,
// ~69K line-events/CU), and each row's 6 global loads fed a dependent FIR
// (~500-900cy chained latency, VALUBusy 12.8%).
// New: block = one (bc, 65-row strip) of 256 threads.
//  - per row: stage 256 dwords to LDS, coalesced 4B/lane (two 512B segs)
//  - E/O split LDS -> conflict-free writes; window = 2x ds_read2_b32
//  - vertical 4-tap via rolling registers; stores lane-consecutive
//    (4 lines/wave-instr, 8x fewer write transactions)
//  - latency: register prefetch ring depth PF=4 (counted vmcnt) +
//    LDS double-buffer, 1 barrier/row
//  - 512 bc x 4 strips = 2048 blocks = 8/CU (one residency round);
//    __launch_bounds__(256,8) pins VGPR<=64. LDS 2.1KB/block.
// HBM floor ~44us (139MB read + 137MB write @ 6.3TB/s); LDS ~16us,
// VALU ~9us -> all under the memory roof.
constexpr int Hn = 128;
constexpr int Wn = 128;
constexpr int SH = 2 * Hn;   // 256 shuffled rows
constexpr int OH = SH + 1;   // 257
constexpr int OW = 257;
constexpr int HW = Hn * Wn;  // input plane stride
constexpr int TY = 65;       // output rows per block
constexpr int NSTRIP = 4;    // 4*65 = 260 >= 257
constexpr int NBC = 16 * 32; // 512 (b,c) planes
constexpr int PF = 4;        // prefetch depth (rows in flight)
constexpr int NIT = TY + 3;  // 68 staged rows per strip

__global__ __launch_bounds__(256, 8) void upsamp_fir_lds(
    const float* __restrict__ x,
    const float* __restrict__ k4,
    float* __restrict__ out)
{
    const int tix = threadIdx.x;
    const int bc  = blockIdx.x;
    const int oh0 = blockIdx.y * TY;
    const float* xp = x + (size_t)bc * 4 * HW;

    // Separable taps (flipped for true convolution), exact for this kernel.
    float fh[4], fv[4];
#pragma unroll
    for (int j = 0; j < 4; ++j) fh[j] = k4[j] + k4[4+j] + k4[8+j] + k4[12+j];
#pragma unroll
    for (int i = 0; i < 4; ++i) fv[i] = k4[4*i] + k4[4*i+1] + k4[4*i+2] + k4[4*i+3];
    const float h0 = fh[3], h1 = fh[2], h2 = fh[1], h3 = fh[0];
    const float g0 = fv[3], g1 = fv[2], g2 = fv[1], g3 = fv[0];

    // LDS: [buf][E/O][132]. EB[1+j] = shuffled col 2j, OB[1+j] = col 2j+1.
    // EB[0]/OB[0] = cols -2/-1 (zero), EB[129]/OB[129] = cols 256/257 (zero).
    __shared__ float lds[2][2][132];
    if (tix < 8) {
        int b = tix >> 2, r = tix & 3;
        lds[b][r >> 1][(r & 1) ? 129 : 0] = 0.f;
    }

    // Staging role: threads 0..127 load even plane dword (tix), 128..255 odd.
    const int eo       = tix < 128 ? 0 : 1;
    const int lane     = tix & 127;
    const int stageIdx = 1 + lane;

    auto xload = [&](int s) -> float {
        // shuffled row s: planes 2*(s&1) (+1 for odd cols), input row s>>1
        return xp[(size_t)(2 * (s & 1) + eo) * HW + (size_t)(s >> 1) * Wn + lane];
    };

    // Output column owned by this thread (plus col 256 for tix==255).
    const int c    = tix;
    const int mi   = c >> 1;
    const int codd = c & 1;
    const bool edge = (tix == 255);

    float* const obase = out + (size_t)bc * OH * OW;

    // Prologue: rows oh0-2 .. oh0+1 into the 4-slot ring.
    float rr0 = 0, rr1 = 0, rr2 = 0, rr3 = 0;
    { int s = oh0 - 2; if ((unsigned)s < (unsigned)SH) rr0 = xload(s); }
    { int s = oh0 - 1; if ((unsigned)s < (unsigned)SH) rr1 = xload(s); }
    { int s = oh0;     if ((unsigned)s < (unsigned)SH) rr2 = xload(s); }
    { int s = oh0 + 1; if ((unsigned)s < (unsigned)SH) rr3 = xload(s); }

    // Rolling horizontal-FIR rows: hm1 = h(s-1), hm2 = h(s-2), hm3 = h(s-3).
    float hm3 = 0, hm2 = 0, hm1 = 0;
    float em3 = 0, em2 = 0, em1 = 0;   // same, for col 256 (edge thread)

    auto step = [&](int m, float& rr, int buf) {
        const int s = oh0 - 2 + m;          // shuffled row staged this iter
        // Stage current row (value prefetched PF iters ago; 0 if OOB).
        lds[buf][eo][stageIdx] = rr;
        // Prefetch row s+PF into the freed ring slot.
        float nv = 0.f;
        const int sp = s + PF;
        if (m < NIT - PF && sp < SH) nv = xload(sp);
        rr = nv;
        __syncthreads();
        // Horizontal FIR at col c: window cols c-2..c+1 via E/O pair reads.
        const float* EB = lds[buf][0];
        const float* OB = lds[buf][1];
        // even c: reads EB[mi],OB[mi],EB[mi+1],OB[mi+1]
        // odd  c: reads OB[mi],EB[mi+1],OB[mi+1],EB[mi+2]
        const float* P = codd ? (OB + mi) : (EB + mi);
        const float* Q = codd ? (EB + mi + 1) : (OB + mi);
        const float p0 = P[0], p1 = P[1];   // -> ds_read2_b32
        const float q0 = Q[0], q1 = Q[1];   // -> ds_read2_b32
        const float hn = h0*p0 + h1*q0 + h2*p1 + h3*q1;
        float en = 0.f;
        if (edge) {                          // col 256: EB[129]/OB[129] are 0
            en = h0*EB[128] + h1*OB[128] + h2*EB[129] + h3*OB[129];
        }
        // Emit output row oh = s-1 (needs h rows s-3..s).
        if (m >= 3) {
            const int oh = oh0 + m - 3;
            if (oh < OH) {
                float* p = obase + (size_t)oh * OW;
                p[c] = g0*hm3 + g1*hm2 + g2*hm1 + g3*hn;   // coalesced
                if (edge) p[256] = g0*em3 + g1*em2 + g2*em1 + g3*en;
            }
        }
        hm3 = hm2; hm2 = hm1; hm1 = hn;
        em3 = em2; em2 = em1; em1 = en;
    };

    // NIT=68 iterations; unrolled by 4 so ring slots & buffers are static
    // (rule: runtime-indexed register arrays spill to scratch).
    for (int mm = 0; mm < NIT; mm += 4) {
        step(mm + 0, rr0, 0);
        step(mm + 1, rr1, 1);
        step(mm + 2, rr2, 0);
        step(mm + 3, rr3, 1);
    }
}

extern "C" void kernel_launch(void* const* d_in, const int* in_sizes, int n_in,
                              void* d_out, int out_size, void* d_ws, size_t ws_size,
                              hipStream_t stream)
{
    const float* x  = (const float*)d_in[0];
    const float* k4 = (const float*)d_in[1];
    float* out      = (float*)d_out;

    dim3 grid(NBC, NSTRIP, 1);
    upsamp_fir_lds<<<grid, dim3(256), 0, stream>>>(x, k4, out);
}